// Round 1
// baseline (958.369 us; speedup 1.0000x reference)
//
#include <hip/hip_runtime.h>
#include <stdint.h>

#define HMAP   (1u << 19)
#define HMASK  (HMAP - 1u)

typedef short bf16x8 __attribute__((ext_vector_type(8)));
typedef float f32x4  __attribute__((ext_vector_type(4)));

// resolutions: ceil(16 * 2^(7l/15)); dense (R^3 <= 2^19) for levels 0..4
__device__ __constant__ const int c_res[16] = {16, 23, 31, 43, 59, 81, 112, 154, 213, 295, 407, 562, 777, 1073, 1483, 2048};

__device__ __forceinline__ unsigned short f2bf(float f) {
    unsigned u = __float_as_uint(f);
    u += 0x7fffu + ((u >> 16) & 1u);           // round-to-nearest-even
    return (unsigned short)(u >> 16);
}

// Exactly matches where(100v>20, v, log1p(exp(100v))/100):
__device__ __forceinline__ float softplus100(float v) {
    return fmaxf(v, 0.f) + 0.01f * __logf(1.f + __expf(-100.f * fabsf(v)));
}

__device__ __forceinline__ bf16x8 cvt8(const float* __restrict__ p) {
    f32x4 a = *(const f32x4*)p;
    f32x4 b = *(const f32x4*)(p + 4);
    bf16x8 r;
    r[0] = f2bf(a[0]); r[1] = f2bf(a[1]); r[2] = f2bf(a[2]); r[3] = f2bf(a[3]);
    r[4] = f2bf(b[0]); r[5] = f2bf(b[1]); r[6] = f2bf(b[2]); r[7] = f2bf(b[3]);
    return r;
}

// Trilinear gather with x-corner pair packing (unchanged numerics from the
// verified split kernel). When called with a compile-time R (unrolled level
// loop), the dense/hashed branch and all strides fold to constants.
__device__ __forceinline__ float2 gather_level(const float* __restrict__ tab, int R,
                                               float x0, float x1, float x2) {
    const float Rm1 = (float)(R - 1);
    float px = x0 * Rm1, py = x1 * Rm1, pz = x2 * Rm1;
    float fx = floorf(px), fy = floorf(py), fz = floorf(pz);
    float wx = px - fx, wy = py - fy, wz = pz - fz;
    int ix = (int)fx, iy = (int)fy, iz = (int)fz;
    ix = max(0, min(ix, R - 1)); iy = max(0, min(iy, R - 1)); iz = max(0, min(iz, R - 1));
    int jx = min(ix + 1, R - 1), jy = min(iy + 1, R - 1), jz = min(iz + 1, R - 1);
    float ax = 1.f - wx, ay = 1.f - wy, az = 1.f - wz;
    float wyz0 = ay * az, wyz1 = wy * az, wyz2 = ay * wz, wyz3 = wy * wz;
    float2 lo[4], hi[4];
    const bool adj = (jx == ix + 1);
    if ((long long)R * R * R <= (long long)HMAP) {   // dense
        unsigned sy = (unsigned)R, sz = (unsigned)(R * R);
        unsigned base0 = (unsigned)iy * sy + (unsigned)iz * sz;
        unsigned base1 = (unsigned)jy * sy + (unsigned)iz * sz;
        unsigned base2 = (unsigned)iy * sy + (unsigned)jz * sz;
        unsigned base3 = (unsigned)jy * sy + (unsigned)jz * sz;
        unsigned bases[4] = {base0, base1, base2, base3};
        const float2* t2 = (const float2*)tab;
        #pragma unroll
        for (int k = 0; k < 4; ++k) {
            unsigned i0 = bases[k] + (unsigned)ix;
            if (adj && !(i0 & 1u)) {
                f32x4 q = *(const f32x4*)(tab + ((size_t)i0 << 1));
                lo[k] = make_float2(q[0], q[1]);
                hi[k] = make_float2(q[2], q[3]);
            } else {
                lo[k] = t2[i0];
                hi[k] = t2[bases[k] + (unsigned)jx];
            }
        }
    } else {                                          // hashed
        unsigned hy0 = (unsigned)iy * 2654435761u, hy1 = (unsigned)jy * 2654435761u;
        unsigned hz0 = (unsigned)iz * 805459861u,  hz1 = (unsigned)jz * 805459861u;
        unsigned m0 = hy0 ^ hz0, m1 = hy1 ^ hz0, m2 = hy0 ^ hz1, m3 = hy1 ^ hz1;
        unsigned ms[4] = {m0, m1, m2, m3};
        if (adj && ((ix & 1) == 0)) {
            #pragma unroll
            for (int k = 0; k < 4; ++k) {
                unsigned h = ((unsigned)ix ^ ms[k]) & HMASK;
                f32x4 q = *(const f32x4*)(tab + ((size_t)(h & ~1u) << 1));
                float2 e0 = make_float2(q[0], q[1]);
                float2 e1 = make_float2(q[2], q[3]);
                bool sw = (h & 1u) != 0;
                lo[k] = sw ? e1 : e0;
                hi[k] = sw ? e0 : e1;
            }
        } else {
            const float2* t2 = (const float2*)tab;
            #pragma unroll
            for (int k = 0; k < 4; ++k) {
                unsigned hl = ((unsigned)ix ^ ms[k]) & HMASK;
                unsigned hh = ((unsigned)jx ^ ms[k]) & HMASK;
                lo[k] = t2[hl];
                hi[k] = t2[hh];
            }
        }
    }
    float2 r = make_float2(0.f, 0.f);
    float wyz[4] = {wyz0, wyz1, wyz2, wyz3};
    #pragma unroll
    for (int k = 0; k < 4; ++k) {
        float wl = ax * wyz[k], wh = wx * wyz[k];
        r.x += wl * lo[k].x + wh * hi[k].x;
        r.y += wl * lo[k].y + wh * hi[k].y;
    }
    return r;
}

// ============== Fused: tiled gather + embed + MFMA MLP in one kernel ==============
// Rationale: the split gather kernel is bound by per-CU divergent-gather request
// throughput (VALU 15%, MFMA 0, HBM 8.5%) while the MLP kernel uses VALU/MFMA with
// almost no vmem. Fusing lets the MLP ride in the gather's stall cycles (m114:
// MFMA/VALU waves co-schedule with vmem-stalled waves at ~max, not sum), and
// deletes the 64MB feat write + 64MB feat read + 15x re-read of x.
#define NPB       128                     // points per tile
#define TILES     4
#define PTS_BLK   (NPB * TILES)           // 512 points per block
#define SA_STRIDE 104                     // shorts; 208B row stride
#define SW0_OFF   (128 * 104)             // W0 bf16 [64][104], cols 71..95 zero
#define SMEM_SHORTS (SW0_OFF + 64 * 104)  // 39936 B -> 4 blocks/CU

__global__ __launch_bounds__(256, 4)
void fused_tiled(const float* __restrict__ x, const float* __restrict__ tables,
                 const float* __restrict__ W0, const float* __restrict__ b0,
                 const float* __restrict__ W1, const float* __restrict__ b1,
                 const float* __restrict__ W2, const float* __restrict__ b2,
                 float* __restrict__ out) {
    __shared__ unsigned short smem[SMEM_SHORTS];
    const int tid  = threadIdx.x;
    const int blk  = blockIdx.x;
    const int wave = tid >> 6, lane = tid & 63;
    const int mhalf = (wave & 1) * 64;
    const int nhalf = (wave >> 1);
    const int lrow = lane & 15, quad = lane >> 4;

    for (int i = tid; i < 64 * 104; i += 256) {
        int n = i / 104, k = i - n * 104;
        smem[SW0_OFF + i] = (k < 71) ? f2bf(W0[n * 71 + k]) : (unsigned short)0;
    }
    for (int i = tid; i < 128 * 25; i += 256) {
        int p = i / 25, k = i - p * 25;
        smem[p * SA_STRIDE + 71 + k] = 0;
    }
    bf16x8 w1f[2][2];
    #pragma unroll
    for (int ks = 0; ks < 2; ++ks)
        #pragma unroll
        for (int nt = 0; nt < 2; ++nt) {
            int n = nhalf * 32 + nt * 16 + lrow;
            w1f[ks][nt] = cvt8(W1 + n * 64 + ks * 32 + quad * 8);
        }
    bf16x8 w2f[2];
    {
        int n2 = nhalf * 16 + lrow;
        #pragma unroll
        for (int ks = 0; ks < 2; ++ks) {
            if (n2 < 17) w2f[ks] = cvt8(W2 + n2 * 64 + ks * 32 + quad * 8);
            else { bf16x8 z = {0,0,0,0,0,0,0,0}; w2f[ks] = z; }
        }
    }
    float b0v[2], b1v[2], b2v;
    #pragma unroll
    for (int nt = 0; nt < 2; ++nt) {
        b0v[nt] = b0[nhalf * 32 + nt * 16 + lrow];
        b1v[nt] = b1[nhalf * 32 + nt * 16 + lrow];
    }
    { int c2 = nhalf * 16 + lrow; b2v = (c2 < 17) ? b2[c2] : 0.f; }
    __syncthreads();

    const size_t pbase0 = (size_t)blk * PTS_BLK;
    #pragma unroll 1
    for (int t = 0; t < TILES; ++t) {
        const size_t pb = pbase0 + (size_t)t * NPB;
        {
            const int p = tid & 127;
            const size_t gp = pb + p;
            unsigned short* row = &smem[p * SA_STRIDE];
            const float x0 = x[3 * gp];
            const float x1 = x[3 * gp + 1];
            const float x2 = x[3 * gp + 2];
            if (tid < 128) {
                row[0] = f2bf(x0); row[1] = f2bf(x1); row[2] = f2bf(x2);
                float fr = 1.f;
                #pragma unroll
                for (int m = 0; m < 6; ++m) {
                    row[3 + 6 * m + 0] = f2bf(__sinf(x0 * fr));
                    row[3 + 6 * m + 1] = f2bf(__sinf(x1 * fr));
                    row[3 + 6 * m + 2] = f2bf(__sinf(x2 * fr));
                    fr *= 2.f;
                }
                #pragma unroll
                for (int li = 0; li < 8; ++li) {
                    const int l = 2 * li;
                    float2 f = gather_level(tables + (size_t)l * (2u * HMAP), c_res[l], x0, x1, x2);
                    row[39 + 2 * l] = f2bf(f.x);
                    row[40 + 2 * l] = f2bf(f.y);
                }
            } else {
                float fr = 1.f;
                #pragma unroll
                for (int m = 0; m < 6; ++m) {
                    row[3 + 6 * m + 3] = f2bf(__cosf(x0 * fr));
                    row[3 + 6 * m + 4] = f2bf(__cosf(x1 * fr));
                    row[3 + 6 * m + 5] = f2bf(__cosf(x2 * fr));
                    fr *= 2.f;
                }
                #pragma unroll
                for (int li = 0; li < 8; ++li) {
                    const int l = 2 * li + 1;
                    float2 f = gather_level(tables + (size_t)l * (2u * HMAP), c_res[l], x0, x1, x2);
                    row[39 + 2 * l] = f2bf(f.x);
                    row[40 + 2 * l] = f2bf(f.y);
                }
            }
        }
        __syncthreads();

        f32x4 acc0[4][2];
        #pragma unroll
        for (int mt = 0; mt < 4; ++mt)
            #pragma unroll
            for (int nt = 0; nt < 2; ++nt) acc0[mt][nt] = (f32x4){0.f, 0.f, 0.f, 0.f};
        #pragma unroll
        for (int ks = 0; ks < 3; ++ks) {
            bf16x8 bfr[2];
            #pragma unroll
            for (int nt = 0; nt < 2; ++nt) {
                int n = nhalf * 32 + nt * 16 + lrow;
                bfr[nt] = *(const bf16x8*)&smem[SW0_OFF + n * 104 + ks * 32 + quad * 8];
            }
            #pragma unroll
            for (int mt = 0; mt < 4; ++mt) {
                int m = mhalf + mt * 16 + lrow;
                bf16x8 afr = *(const bf16x8*)&smem[m * SA_STRIDE + ks * 32 + quad * 8];
                #pragma unroll
                for (int nt = 0; nt < 2; ++nt)
                    acc0[mt][nt] = __builtin_amdgcn_mfma_f32_16x16x32_bf16(afr, bfr[nt], acc0[mt][nt], 0, 0, 0);
            }
        }
        __syncthreads();
        #pragma unroll
        for (int mt = 0; mt < 4; ++mt)
            #pragma unroll
            for (int nt = 0; nt < 2; ++nt) {
                int colg = nhalf * 32 + nt * 16 + lrow;
                #pragma unroll
                for (int r = 0; r < 4; ++r) {
                    int rowm = mhalf + mt * 16 + quad * 4 + r;
                    smem[rowm * SA_STRIDE + colg] = f2bf(softplus100(acc0[mt][nt][r] + b0v[nt]));
                }
            }
        __syncthreads();

        f32x4 acc1[4][2];
        #pragma unroll
        for (int mt = 0; mt < 4; ++mt)
            #pragma unroll
            for (int nt = 0; nt < 2; ++nt) acc1[mt][nt] = (f32x4){0.f, 0.f, 0.f, 0.f};
        #pragma unroll
        for (int ks = 0; ks < 2; ++ks) {
            #pragma unroll
            for (int mt = 0; mt < 4; ++mt) {
                int m = mhalf + mt * 16 + lrow;
                bf16x8 afr = *(const bf16x8*)&smem[m * SA_STRIDE + ks * 32 + quad * 8];
                #pragma unroll
                for (int nt = 0; nt < 2; ++nt)
                    acc1[mt][nt] = __builtin_amdgcn_mfma_f32_16x16x32_bf16(afr, w1f[ks][nt], acc1[mt][nt], 0, 0, 0);
            }
        }
        __syncthreads();
        #pragma unroll
        for (int mt = 0; mt < 4; ++mt)
            #pragma unroll
            for (int nt = 0; nt < 2; ++nt) {
                int colg = nhalf * 32 + nt * 16 + lrow;
                #pragma unroll
                for (int r = 0; r < 4; ++r) {
                    int rowm = mhalf + mt * 16 + quad * 4 + r;
                    smem[rowm * SA_STRIDE + colg] = f2bf(softplus100(acc1[mt][nt][r] + b1v[nt]));
                }
            }
        __syncthreads();

        f32x4 acc2[4];
        #pragma unroll
        for (int mt = 0; mt < 4; ++mt) acc2[mt] = (f32x4){0.f, 0.f, 0.f, 0.f};
        #pragma unroll
        for (int ks = 0; ks < 2; ++ks) {
            #pragma unroll
            for (int mt = 0; mt < 4; ++mt) {
                int m = mhalf + mt * 16 + lrow;
                bf16x8 afr = *(const bf16x8*)&smem[m * SA_STRIDE + ks * 32 + quad * 8];
                acc2[mt] = __builtin_amdgcn_mfma_f32_16x16x32_bf16(afr, w2f[ks], acc2[mt], 0, 0, 0);
            }
        }
        {
            int colg = nhalf * 16 + lrow;
            if (colg < 17) {
                #pragma unroll
                for (int mt = 0; mt < 4; ++mt)
                    #pragma unroll
                    for (int r = 0; r < 4; ++r) {
                        int rowm = mhalf + mt * 16 + quad * 4 + r;
                        __builtin_nontemporal_store(acc2[mt][r] + b2v,
                                                    out + (pb + rowm) * 17 + colg);
                    }
            }
        }
        __syncthreads();
    }
}

extern "C" void kernel_launch(void* const* d_in, const int* in_sizes, int n_in,
                              void* d_out, int out_size, void* d_ws, size_t ws_size,
                              hipStream_t stream) {
    const float* x      = (const float*)d_in[0];
    const float* tables = (const float*)d_in[1];
    const float* W0     = (const float*)d_in[2];
    const float* b0     = (const float*)d_in[3];
    const float* W1     = (const float*)d_in[4];
    const float* b1     = (const float*)d_in[5];
    const float* W2     = (const float*)d_in[6];
    const float* b2     = (const float*)d_in[7];
    float* out = (float*)d_out;
    const int n = in_sizes[0] / 3;                       // 1048576
    fused_tiled<<<dim3(n / PTS_BLK), dim3(256), 0, stream>>>(x, tables, W0, b0, W1, b1, W2, b2, out);
}

// Round 3
// 597.813 us; speedup vs baseline: 1.6031x; 1.6031x over previous
//
#include <hip/hip_runtime.h>
#include <stdint.h>

#define HMAP   (1u << 19)
#define HMASK  (HMAP - 1u)

typedef short bf16x8 __attribute__((ext_vector_type(8)));
typedef float f32x4  __attribute__((ext_vector_type(4)));
typedef float f32x2  __attribute__((ext_vector_type(2)));
typedef unsigned u32x2 __attribute__((ext_vector_type(2)));

// resolutions: ceil(16 * 2^(7l/15)); dense (R^3 <= 2^19) for levels 0..4
__device__ __constant__ const int c_res[16] = {16, 23, 31, 43, 59, 81, 112, 154, 213, 295, 407, 562, 777, 1073, 1483, 2048};

__device__ __forceinline__ unsigned short f2bf(float f) {
    unsigned u = __float_as_uint(f);
    u += 0x7fffu + ((u >> 16) & 1u);           // round-to-nearest-even
    return (unsigned short)(u >> 16);
}

// Exactly matches where(100v>20, v, log1p(exp(100v))/100):
__device__ __forceinline__ float softplus100(float v) {
    return fmaxf(v, 0.f) + 0.01f * __logf(1.f + __expf(-100.f * fabsf(v)));
}

__device__ __forceinline__ bf16x8 cvt8(const float* __restrict__ p) {
    f32x4 a = *(const f32x4*)p;
    f32x4 b = *(const f32x4*)(p + 4);
    bf16x8 r;
    r[0] = f2bf(a[0]); r[1] = f2bf(a[1]); r[2] = f2bf(a[2]); r[3] = f2bf(a[3]);
    r[4] = f2bf(b[0]); r[5] = f2bf(b[1]); r[6] = f2bf(b[2]); r[7] = f2bf(b[3]);
    return r;
}

// Single-point trilinear gather (used by the no-workspace fallback only).
__device__ __forceinline__ float2 gather_level(const float* __restrict__ tab, int R,
                                               float x0, float x1, float x2) {
    const float Rm1 = (float)(R - 1);
    float px = x0 * Rm1, py = x1 * Rm1, pz = x2 * Rm1;
    float fx = floorf(px), fy = floorf(py), fz = floorf(pz);
    float wx = px - fx, wy = py - fy, wz = pz - fz;
    int ix = (int)fx, iy = (int)fy, iz = (int)fz;
    ix = max(0, min(ix, R - 1)); iy = max(0, min(iy, R - 1)); iz = max(0, min(iz, R - 1));
    int jx = min(ix + 1, R - 1), jy = min(iy + 1, R - 1), jz = min(iz + 1, R - 1);
    float ax = 1.f - wx, ay = 1.f - wy, az = 1.f - wz;
    float wyz0 = ay * az, wyz1 = wy * az, wyz2 = ay * wz, wyz3 = wy * wz;
    float2 lo[4], hi[4];
    const bool adj = (jx == ix + 1);
    if ((long long)R * R * R <= (long long)HMAP) {   // dense
        unsigned sy = (unsigned)R, sz = (unsigned)(R * R);
        unsigned bases[4] = {(unsigned)iy * sy + (unsigned)iz * sz,
                             (unsigned)jy * sy + (unsigned)iz * sz,
                             (unsigned)iy * sy + (unsigned)jz * sz,
                             (unsigned)jy * sy + (unsigned)jz * sz};
        const float2* t2 = (const float2*)tab;
        #pragma unroll
        for (int k = 0; k < 4; ++k) {
            unsigned i0 = bases[k] + (unsigned)ix;
            if (adj && !(i0 & 1u)) {
                f32x4 q = *(const f32x4*)(tab + ((size_t)i0 << 1));
                lo[k] = make_float2(q[0], q[1]);
                hi[k] = make_float2(q[2], q[3]);
            } else {
                lo[k] = t2[i0];
                hi[k] = t2[bases[k] + (unsigned)jx];
            }
        }
    } else {                                          // hashed
        unsigned hy0 = (unsigned)iy * 2654435761u, hy1 = (unsigned)jy * 2654435761u;
        unsigned hz0 = (unsigned)iz * 805459861u,  hz1 = (unsigned)jz * 805459861u;
        unsigned ms[4] = {hy0 ^ hz0, hy1 ^ hz0, hy0 ^ hz1, hy1 ^ hz1};
        if (adj && ((ix & 1) == 0)) {
            #pragma unroll
            for (int k = 0; k < 4; ++k) {
                unsigned h = ((unsigned)ix ^ ms[k]) & HMASK;
                f32x4 q = *(const f32x4*)(tab + ((size_t)(h & ~1u) << 1));
                float2 e0 = make_float2(q[0], q[1]);
                float2 e1 = make_float2(q[2], q[3]);
                bool sw = (h & 1u) != 0;
                lo[k] = sw ? e1 : e0;
                hi[k] = sw ? e0 : e1;
            }
        } else {
            const float2* t2 = (const float2*)tab;
            #pragma unroll
            for (int k = 0; k < 4; ++k) {
                unsigned hl = ((unsigned)ix ^ ms[k]) & HMASK;
                unsigned hh = ((unsigned)jx ^ ms[k]) & HMASK;
                lo[k] = t2[hl];
                hi[k] = t2[hh];
            }
        }
    }
    float2 r = make_float2(0.f, 0.f);
    float wyz[4] = {wyz0, wyz1, wyz2, wyz3};
    #pragma unroll
    for (int k = 0; k < 4; ++k) {
        float wl = ax * wyz[k], wh = wx * wyz[k];
        r.x += wl * lo[k].x + wh * hi[k].x;
        r.y += wl * lo[k].y + wh * hi[k].y;
    }
    return r;
}

// Two-point gather, same level: addresses for both points computed first, all
// 8-16 loads issued as one cluster (2x memory-level parallelism vs 1-pt), then
// both reductions. Same numerics & same L2 locality as gather_level.
__device__ __forceinline__ void gather2(const float* __restrict__ tab, int R,
                                        float x0A, float x1A, float x2A,
                                        float x0B, float x1B, float x2B,
                                        float2& rA, float2& rB) {
    const float Rm1 = (float)(R - 1);
    float wxv[2], axv[2];
    float wyz[2][4];
    float2 lo[2][4], hi[2][4];
    int ixv[2], jxv[2];
    unsigned basev[2][4];   // dense yz-bases or hash yz-masks
    const bool dense = (long long)R * R * R <= (long long)HMAP;
    #pragma unroll
    for (int t = 0; t < 2; ++t) {
        const float X0 = t ? x0B : x0A, X1 = t ? x1B : x1A, X2 = t ? x2B : x2A;
        float px = X0 * Rm1, py = X1 * Rm1, pz = X2 * Rm1;
        float fx = floorf(px), fy = floorf(py), fz = floorf(pz);
        float wx = px - fx, wy = py - fy, wz = pz - fz;
        int ix = (int)fx, iy = (int)fy, iz = (int)fz;
        ix = max(0, min(ix, R - 1)); iy = max(0, min(iy, R - 1)); iz = max(0, min(iz, R - 1));
        int jx = min(ix + 1, R - 1), jy = min(iy + 1, R - 1), jz = min(iz + 1, R - 1);
        float ax = 1.f - wx, ay = 1.f - wy, az = 1.f - wz;
        wyz[t][0] = ay * az; wyz[t][1] = wy * az; wyz[t][2] = ay * wz; wyz[t][3] = wy * wz;
        wxv[t] = wx; axv[t] = ax; ixv[t] = ix; jxv[t] = jx;
        if (dense) {
            unsigned sy = (unsigned)R, sz = (unsigned)(R * R);
            basev[t][0] = (unsigned)iy * sy + (unsigned)iz * sz;
            basev[t][1] = (unsigned)jy * sy + (unsigned)iz * sz;
            basev[t][2] = (unsigned)iy * sy + (unsigned)jz * sz;
            basev[t][3] = (unsigned)jy * sy + (unsigned)jz * sz;
        } else {
            unsigned hy0 = (unsigned)iy * 2654435761u, hy1 = (unsigned)jy * 2654435761u;
            unsigned hz0 = (unsigned)iz * 805459861u,  hz1 = (unsigned)jz * 805459861u;
            basev[t][0] = hy0 ^ hz0; basev[t][1] = hy1 ^ hz0;
            basev[t][2] = hy0 ^ hz1; basev[t][3] = hy1 ^ hz1;
        }
    }
    if (dense) {
        const float2* t2 = (const float2*)tab;
        #pragma unroll
        for (int t = 0; t < 2; ++t) {
            const bool adj = (jxv[t] == ixv[t] + 1);
            #pragma unroll
            for (int k = 0; k < 4; ++k) {
                unsigned i0 = basev[t][k] + (unsigned)ixv[t];
                if (adj && !(i0 & 1u)) {
                    f32x4 q = *(const f32x4*)(tab + ((size_t)i0 << 1));
                    lo[t][k] = make_float2(q[0], q[1]);
                    hi[t][k] = make_float2(q[2], q[3]);
                } else {
                    lo[t][k] = t2[i0];
                    hi[t][k] = t2[basev[t][k] + (unsigned)jxv[t]];
                }
            }
        }
    } else {
        const float2* t2 = (const float2*)tab;
        #pragma unroll
        for (int t = 0; t < 2; ++t) {
            const bool adj = (jxv[t] == ixv[t] + 1) && ((ixv[t] & 1) == 0);
            #pragma unroll
            for (int k = 0; k < 4; ++k) {
                if (adj) {
                    unsigned h = ((unsigned)ixv[t] ^ basev[t][k]) & HMASK;
                    f32x4 q = *(const f32x4*)(tab + ((size_t)(h & ~1u) << 1));
                    float2 e0 = make_float2(q[0], q[1]);
                    float2 e1 = make_float2(q[2], q[3]);
                    bool sw = (h & 1u) != 0;
                    lo[t][k] = sw ? e1 : e0;
                    hi[t][k] = sw ? e0 : e1;
                } else {
                    unsigned hl = ((unsigned)ixv[t] ^ basev[t][k]) & HMASK;
                    unsigned hh = ((unsigned)jxv[t] ^ basev[t][k]) & HMASK;
                    lo[t][k] = t2[hl];
                    hi[t][k] = t2[hh];
                }
            }
        }
    }
    float2 res[2];
    #pragma unroll
    for (int t = 0; t < 2; ++t) {
        float2 r = make_float2(0.f, 0.f);
        #pragma unroll
        for (int k = 0; k < 4; ++k) {
            float wl = axv[t] * wyz[t][k], wh = wxv[t] * wyz[t][k];
            r.x += wl * lo[t][k].x + wh * hi[t][k].x;
            r.y += wl * lo[t][k].y + wh * hi[t][k].y;
        }
        res[t] = r;
    }
    rA = res[0]; rB = res[1];
}

// ======================= Kernel 1: per-(point-pair,level) gather =======================
// phase0: level = b%8 (levels 0-7); phase1: level = 15-(b%8) -> XCD k serves levels
// {k, 15-k}, each table L2-resident on one XCD (verified: fusing broke this and
// FETCH went 0.19->3.0 GB). Each thread handles 2 consecutive points:
// 2x gather MLP, x loads as 3 aligned dwordx2, feat store as 1 dwordx2.
__global__ __launch_bounds__(256, 6)
void gather_levels(const float* __restrict__ x, const float* __restrict__ tables,
                   unsigned* __restrict__ feat, int N, int C) {
    const int b = blockIdx.x;
    const int half = 8 * C;
    int r, level;
    if (b < half) { r = b; level = r & 7; }
    else          { r = b - half; level = 15 - (r & 7); }
    const size_t p0 = (size_t)(r >> 3) * 512 + 2u * threadIdx.x;
    const f32x2* xv = (const f32x2*)(x + 3 * p0);     // byte offset 12*p0, p0 even -> 8B aligned
    f32x2 u0 = __builtin_nontemporal_load(xv);
    f32x2 u1 = __builtin_nontemporal_load(xv + 1);
    f32x2 u2 = __builtin_nontemporal_load(xv + 2);
    float2 fA, fB;
    gather2(tables + (size_t)level * (2u * HMAP), c_res[level],
            u0[0], u0[1], u1[0],            // point p0
            u1[1], u2[0], u2[1],            // point p0+1
            fA, fB);
    u32x2 v;
    v[0] = (unsigned)f2bf(fA.x) | ((unsigned)f2bf(fA.y) << 16);
    v[1] = (unsigned)f2bf(fB.x) | ((unsigned)f2bf(fB.y) << 16);
    __builtin_nontemporal_store(v, (u32x2*)(feat + (size_t)level * N + p0));
}

// ======================= Kernel 2: tiled embed + MFMA MLP =======================
#define NPB       128                     // points per tile
#define TILES     8
#define PTS_BLK   (NPB * TILES)           // 1024 points per block
#define SA_STRIDE 104                     // shorts; 208B row stride (2-way banks, free)
#define SW0_OFF   (128 * 104)             // W0 bf16 [64][104], cols 71..95 zero
#define SMEM_SHORTS (SW0_OFF + 64 * 104)  // 39936 B -> 4 blocks/CU

__global__ __launch_bounds__(256, 4)
void mlp_tiled(const float* __restrict__ x, const unsigned* __restrict__ feat,
               const float* __restrict__ W0, const float* __restrict__ b0,
               const float* __restrict__ W1, const float* __restrict__ b1,
               const float* __restrict__ W2, const float* __restrict__ b2,
               float* __restrict__ out, int N) {
    __shared__ unsigned short smem[SMEM_SHORTS];
    const int tid  = threadIdx.x;
    const int blk  = blockIdx.x;
    const int wave = tid >> 6, lane = tid & 63;
    const int mhalf = (wave & 1) * 64;
    const int nhalf = (wave >> 1);
    const int lrow = lane & 15, quad = lane >> 4;

    for (int i = tid; i < 64 * 104; i += 256) {
        int n = i / 104, k = i - n * 104;
        smem[SW0_OFF + i] = (k < 71) ? f2bf(W0[n * 71 + k]) : (unsigned short)0;
    }
    for (int i = tid; i < 128 * 25; i += 256) {
        int p = i / 25, k = i - p * 25;
        smem[p * SA_STRIDE + 71 + k] = 0;
    }
    bf16x8 w1f[2][2];
    #pragma unroll
    for (int ks = 0; ks < 2; ++ks)
        #pragma unroll
        for (int nt = 0; nt < 2; ++nt) {
            int n = nhalf * 32 + nt * 16 + lrow;
            w1f[ks][nt] = cvt8(W1 + n * 64 + ks * 32 + quad * 8);
        }
    bf16x8 w2f[2];
    {
        int n2 = nhalf * 16 + lrow;
        #pragma unroll
        for (int ks = 0; ks < 2; ++ks) {
            if (n2 < 17) w2f[ks] = cvt8(W2 + n2 * 64 + ks * 32 + quad * 8);
            else { bf16x8 z = {0,0,0,0,0,0,0,0}; w2f[ks] = z; }
        }
    }
    float b0v[2], b1v[2], b2v;
    #pragma unroll
    for (int nt = 0; nt < 2; ++nt) {
        b0v[nt] = b0[nhalf * 32 + nt * 16 + lrow];
        b1v[nt] = b1[nhalf * 32 + nt * 16 + lrow];
    }
    { int c2 = nhalf * 16 + lrow; b2v = (c2 < 17) ? b2[c2] : 0.f; }
    __syncthreads();

    const size_t pbase0 = (size_t)blk * PTS_BLK;
    #pragma unroll 1
    for (int t = 0; t < TILES; ++t) {
        const size_t pb = pbase0 + (size_t)t * NPB;
        {
            const int p = tid & 127;
            const size_t gp = pb + p;
            unsigned short* row = &smem[p * SA_STRIDE];
            const float x0 = __builtin_nontemporal_load(x + 3 * gp);
            const float x1 = __builtin_nontemporal_load(x + 3 * gp + 1);
            const float x2 = __builtin_nontemporal_load(x + 3 * gp + 2);
            if (tid < 128) {
                row[0] = f2bf(x0); row[1] = f2bf(x1); row[2] = f2bf(x2);
                float fr = 1.f;
                #pragma unroll
                for (int m = 0; m < 6; ++m) {
                    row[3 + 6 * m + 0] = f2bf(__sinf(x0 * fr));
                    row[3 + 6 * m + 1] = f2bf(__sinf(x1 * fr));
                    row[3 + 6 * m + 2] = f2bf(__sinf(x2 * fr));
                    fr *= 2.f;
                }
            } else {
                float fr = 1.f;
                #pragma unroll
                for (int m = 0; m < 6; ++m) {
                    row[3 + 6 * m + 3] = f2bf(__cosf(x0 * fr));
                    row[3 + 6 * m + 4] = f2bf(__cosf(x1 * fr));
                    row[3 + 6 * m + 5] = f2bf(__cosf(x2 * fr));
                    fr *= 2.f;
                }
                #pragma unroll
                for (int l = 0; l < 16; ++l) {
                    unsigned v = __builtin_nontemporal_load(feat + (size_t)l * N + gp);
                    row[39 + 2 * l] = (unsigned short)(v & 0xffffu);
                    row[40 + 2 * l] = (unsigned short)(v >> 16);
                }
            }
        }
        __syncthreads();

        f32x4 acc0[4][2];
        #pragma unroll
        for (int mt = 0; mt < 4; ++mt)
            #pragma unroll
            for (int nt = 0; nt < 2; ++nt) acc0[mt][nt] = (f32x4){0.f, 0.f, 0.f, 0.f};
        #pragma unroll
        for (int ks = 0; ks < 3; ++ks) {
            bf16x8 bfr[2];
            #pragma unroll
            for (int nt = 0; nt < 2; ++nt) {
                int n = nhalf * 32 + nt * 16 + lrow;
                bfr[nt] = *(const bf16x8*)&smem[SW0_OFF + n * 104 + ks * 32 + quad * 8];
            }
            #pragma unroll
            for (int mt = 0; mt < 4; ++mt) {
                int m = mhalf + mt * 16 + lrow;
                bf16x8 afr = *(const bf16x8*)&smem[m * SA_STRIDE + ks * 32 + quad * 8];
                #pragma unroll
                for (int nt = 0; nt < 2; ++nt)
                    acc0[mt][nt] = __builtin_amdgcn_mfma_f32_16x16x32_bf16(afr, bfr[nt], acc0[mt][nt], 0, 0, 0);
            }
        }
        __syncthreads();
        #pragma unroll
        for (int mt = 0; mt < 4; ++mt)
            #pragma unroll
            for (int nt = 0; nt < 2; ++nt) {
                int colg = nhalf * 32 + nt * 16 + lrow;
                #pragma unroll
                for (int r = 0; r < 4; ++r) {
                    int rowm = mhalf + mt * 16 + quad * 4 + r;
                    smem[rowm * SA_STRIDE + colg] = f2bf(softplus100(acc0[mt][nt][r] + b0v[nt]));
                }
            }
        __syncthreads();

        f32x4 acc1[4][2];
        #pragma unroll
        for (int mt = 0; mt < 4; ++mt)
            #pragma unroll
            for (int nt = 0; nt < 2; ++nt) acc1[mt][nt] = (f32x4){0.f, 0.f, 0.f, 0.f};
        #pragma unroll
        for (int ks = 0; ks < 2; ++ks) {
            #pragma unroll
            for (int mt = 0; mt < 4; ++mt) {
                int m = mhalf + mt * 16 + lrow;
                bf16x8 afr = *(const bf16x8*)&smem[m * SA_STRIDE + ks * 32 + quad * 8];
                #pragma unroll
                for (int nt = 0; nt < 2; ++nt)
                    acc1[mt][nt] = __builtin_amdgcn_mfma_f32_16x16x32_bf16(afr, w1f[ks][nt], acc1[mt][nt], 0, 0, 0);
            }
        }
        __syncthreads();
        #pragma unroll
        for (int mt = 0; mt < 4; ++mt)
            #pragma unroll
            for (int nt = 0; nt < 2; ++nt) {
                int colg = nhalf * 32 + nt * 16 + lrow;
                #pragma unroll
                for (int r = 0; r < 4; ++r) {
                    int rowm = mhalf + mt * 16 + quad * 4 + r;
                    smem[rowm * SA_STRIDE + colg] = f2bf(softplus100(acc1[mt][nt][r] + b1v[nt]));
                }
            }
        __syncthreads();

        f32x4 acc2[4];
        #pragma unroll
        for (int mt = 0; mt < 4; ++mt) acc2[mt] = (f32x4){0.f, 0.f, 0.f, 0.f};
        #pragma unroll
        for (int ks = 0; ks < 2; ++ks) {
            #pragma unroll
            for (int mt = 0; mt < 4; ++mt) {
                int m = mhalf + mt * 16 + lrow;
                bf16x8 afr = *(const bf16x8*)&smem[m * SA_STRIDE + ks * 32 + quad * 8];
                acc2[mt] = __builtin_amdgcn_mfma_f32_16x16x32_bf16(afr, w2f[ks], acc2[mt], 0, 0, 0);
            }
        }
        {
            int colg = nhalf * 16 + lrow;
            if (colg < 17) {
                #pragma unroll
                for (int mt = 0; mt < 4; ++mt)
                    #pragma unroll
                    for (int r = 0; r < 4; ++r) {
                        int rowm = mhalf + mt * 16 + quad * 4 + r;
                        __builtin_nontemporal_store(acc2[mt][r] + b2v,
                                                    out + (pb + rowm) * 17 + colg);
                    }
            }
        }
        __syncthreads();
    }
}

// ======================= Fallback (ws too small): fully fused =======================
__global__ __launch_bounds__(256, 3)
void gn_fused(const float* __restrict__ x, const float* __restrict__ tables,
              const float* __restrict__ W0, const float* __restrict__ b0,
              const float* __restrict__ W1, const float* __restrict__ b1,
              const float* __restrict__ W2, const float* __restrict__ b2,
              float* __restrict__ out) {
    __shared__ unsigned short smem[SMEM_SHORTS];
    const int tid = threadIdx.x;
    const int blk = blockIdx.x;
    const int wave = tid >> 6, lane = tid & 63;
    const int mhalf = (wave & 1) * 64;
    const int nhalf = (wave >> 1);
    const int lrow = lane & 15, quad = lane >> 4;
    for (int i = tid; i < 64 * 104; i += 256) {
        int n = i / 104, k = i - n * 104;
        smem[SW0_OFF + i] = (k < 71) ? f2bf(W0[n * 71 + k]) : (unsigned short)0;
    }
    for (int i = tid; i < 128 * 25; i += 256) {
        int p = i / 25, k = i - p * 25;
        smem[p * SA_STRIDE + 71 + k] = 0;
    }
    bf16x8 w1f[2][2];
    #pragma unroll
    for (int ks = 0; ks < 2; ++ks)
        #pragma unroll
        for (int nt = 0; nt < 2; ++nt) {
            int n = nhalf * 32 + nt * 16 + lrow;
            w1f[ks][nt] = cvt8(W1 + n * 64 + ks * 32 + quad * 8);
        }
    bf16x8 w2f[2];
    {
        int n2 = nhalf * 16 + lrow;
        #pragma unroll
        for (int ks = 0; ks < 2; ++ks) {
            if (n2 < 17) w2f[ks] = cvt8(W2 + n2 * 64 + ks * 32 + quad * 8);
            else { bf16x8 z = {0,0,0,0,0,0,0,0}; w2f[ks] = z; }
        }
    }
    float b0v[2], b1v[2], b2v;
    #pragma unroll
    for (int nt = 0; nt < 2; ++nt) {
        b0v[nt] = b0[nhalf * 32 + nt * 16 + lrow];
        b1v[nt] = b1[nhalf * 32 + nt * 16 + lrow];
    }
    { int c2 = nhalf * 16 + lrow; b2v = (c2 < 17) ? b2[c2] : 0.f; }
    {
        const int p = tid & 127;
        const size_t gp = (size_t)blk * NPB + p;
        const float x0 = x[3 * gp], x1 = x[3 * gp + 1], x2 = x[3 * gp + 2];
        unsigned short* row = &smem[p * SA_STRIDE];
        if (tid < 128) {
            row[0] = f2bf(x0); row[1] = f2bf(x1); row[2] = f2bf(x2);
            float fr = 1.f;
            #pragma unroll
            for (int m = 0; m < 6; ++m) {
                row[3 + 6 * m + 0] = f2bf(__sinf(x0 * fr));
                row[3 + 6 * m + 1] = f2bf(__sinf(x1 * fr));
                row[3 + 6 * m + 2] = f2bf(__sinf(x2 * fr));
                fr *= 2.f;
            }
            #pragma unroll
            for (int li = 0; li < 8; ++li) {
                const int l = 2 * li;
                float2 f = gather_level(tables + (size_t)l * (2u * HMAP), c_res[l], x0, x1, x2);
                row[39 + 2 * l] = f2bf(f.x);
                row[40 + 2 * l] = f2bf(f.y);
            }
        } else {
            float fr = 1.f;
            #pragma unroll
            for (int m = 0; m < 6; ++m) {
                row[3 + 6 * m + 3] = f2bf(__cosf(x0 * fr));
                row[3 + 6 * m + 4] = f2bf(__cosf(x1 * fr));
                row[3 + 6 * m + 5] = f2bf(__cosf(x2 * fr));
                fr *= 2.f;
            }
            #pragma unroll
            for (int li = 0; li < 8; ++li) {
                const int l = 2 * li + 1;
                float2 f = gather_level(tables + (size_t)l * (2u * HMAP), c_res[l], x0, x1, x2);
                row[39 + 2 * l] = f2bf(f.x);
                row[40 + 2 * l] = f2bf(f.y);
            }
        }
    }
    __syncthreads();
    f32x4 acc0[4][2];
    #pragma unroll
    for (int mt = 0; mt < 4; ++mt)
        #pragma unroll
        for (int nt = 0; nt < 2; ++nt) acc0[mt][nt] = (f32x4){0.f, 0.f, 0.f, 0.f};
    #pragma unroll
    for (int ks = 0; ks < 3; ++ks) {
        bf16x8 bfr[2];
        #pragma unroll
        for (int nt = 0; nt < 2; ++nt) {
            int n = nhalf * 32 + nt * 16 + lrow;
            bfr[nt] = *(const bf16x8*)&smem[SW0_OFF + n * 104 + ks * 32 + quad * 8];
        }
        #pragma unroll
        for (int mt = 0; mt < 4; ++mt) {
            int m = mhalf + mt * 16 + lrow;
            bf16x8 afr = *(const bf16x8*)&smem[m * SA_STRIDE + ks * 32 + quad * 8];
            #pragma unroll
            for (int nt = 0; nt < 2; ++nt)
                acc0[mt][nt] = __builtin_amdgcn_mfma_f32_16x16x32_bf16(afr, bfr[nt], acc0[mt][nt], 0, 0, 0);
        }
    }
    __syncthreads();
    #pragma unroll
    for (int mt = 0; mt < 4; ++mt)
        #pragma unroll
        for (int nt = 0; nt < 2; ++nt) {
            int colg = nhalf * 32 + nt * 16 + lrow;
            #pragma unroll
            for (int r = 0; r < 4; ++r) {
                int rowm = mhalf + mt * 16 + quad * 4 + r;
                smem[rowm * SA_STRIDE + colg] = f2bf(softplus100(acc0[mt][nt][r] + b0v[nt]));
            }
        }
    __syncthreads();
    f32x4 acc1[4][2];
    #pragma unroll
    for (int mt = 0; mt < 4; ++mt)
        #pragma unroll
        for (int nt = 0; nt < 2; ++nt) acc1[mt][nt] = (f32x4){0.f, 0.f, 0.f, 0.f};
    #pragma unroll
    for (int ks = 0; ks < 2; ++ks) {
        #pragma unroll
        for (int mt = 0; mt < 4; ++mt) {
            int m = mhalf + mt * 16 + lrow;
            bf16x8 afr = *(const bf16x8*)&smem[m * SA_STRIDE + ks * 32 + quad * 8];
            #pragma unroll
            for (int nt = 0; nt < 2; ++nt)
                acc1[mt][nt] = __builtin_amdgcn_mfma_f32_16x16x32_bf16(afr, w1f[ks][nt], acc1[mt][nt], 0, 0, 0);
        }
    }
    __syncthreads();
    #pragma unroll
    for (int mt = 0; mt < 4; ++mt)
        #pragma unroll
        for (int nt = 0; nt < 2; ++nt) {
            int colg = nhalf * 32 + nt * 16 + lrow;
            #pragma unroll
            for (int r = 0; r < 4; ++r) {
                int rowm = mhalf + mt * 16 + quad * 4 + r;
                smem[rowm * SA_STRIDE + colg] = f2bf(softplus100(acc1[mt][nt][r] + b1v[nt]));
            }
        }
    __syncthreads();
    f32x4 acc2[4];
    #pragma unroll
    for (int mt = 0; mt < 4; ++mt) acc2[mt] = (f32x4){0.f, 0.f, 0.f, 0.f};
    #pragma unroll
    for (int ks = 0; ks < 2; ++ks) {
        #pragma unroll
        for (int mt = 0; mt < 4; ++mt) {
            int m = mhalf + mt * 16 + lrow;
            bf16x8 afr = *(const bf16x8*)&smem[m * SA_STRIDE + ks * 32 + quad * 8];
            acc2[mt] = __builtin_amdgcn_mfma_f32_16x16x32_bf16(afr, w2f[ks], acc2[mt], 0, 0, 0);
        }
    }
    {
        int colg = nhalf * 16 + lrow;
        if (colg < 17) {
            #pragma unroll
            for (int mt = 0; mt < 4; ++mt)
                #pragma unroll
                for (int r = 0; r < 4; ++r) {
                    int rowm = mhalf + mt * 16 + quad * 4 + r;
                    out[((size_t)blk * NPB + rowm) * 17 + colg] = acc2[mt][r] + b2v;
                }
        }
    }
}

extern "C" void kernel_launch(void* const* d_in, const int* in_sizes, int n_in,
                              void* d_out, int out_size, void* d_ws, size_t ws_size,
                              hipStream_t stream) {
    const float* x      = (const float*)d_in[0];
    const float* tables = (const float*)d_in[1];
    const float* W0     = (const float*)d_in[2];
    const float* b0     = (const float*)d_in[3];
    const float* W1     = (const float*)d_in[4];
    const float* b1     = (const float*)d_in[5];
    const float* W2     = (const float*)d_in[6];
    const float* b2     = (const float*)d_in[7];
    float* out = (float*)d_out;
    const int n = in_sizes[0] / 3;                       // 1048576
    const size_t ws_needed = (size_t)16 * n * 4;         // 64 MB feature staging
    if (ws_size >= ws_needed) {
        unsigned* feat = (unsigned*)d_ws;
        const int C = n / 512;                           // point-pairs: 512 pts/block
        gather_levels<<<dim3(16 * C), dim3(256), 0, stream>>>(x, tables, feat, n, C);
        mlp_tiled<<<dim3(n / PTS_BLK), dim3(256), 0, stream>>>(x, feat, W0, b0, W1, b1, W2, b2, out, n);
    } else {
        gn_fused<<<dim3(n / NPB), dim3(256), 0, stream>>>(x, tables, W0, b0, W1, b1, W2, b2, out);
    }
}

// Round 4
// 549.433 us; speedup vs baseline: 1.7443x; 1.0881x over previous
//
#include <hip/hip_runtime.h>
#include <stdint.h>

#define HMAP   (1u << 19)
#define HMASK  (HMAP - 1u)

typedef short bf16x8 __attribute__((ext_vector_type(8)));
typedef float f32x4  __attribute__((ext_vector_type(4)));
typedef float f32x2  __attribute__((ext_vector_type(2)));
typedef unsigned u32x2 __attribute__((ext_vector_type(2)));

// resolutions: ceil(16 * 2^(7l/15)); dense (R^3 <= 2^19) for levels 0..4
__device__ __constant__ const int c_res[16] = {16, 23, 31, 43, 59, 81, 112, 154, 213, 295, 407, 562, 777, 1073, 1483, 2048};

__device__ __forceinline__ unsigned short f2bf(float f) {
    unsigned u = __float_as_uint(f);
    u += 0x7fffu + ((u >> 16) & 1u);           // round-to-nearest-even
    return (unsigned short)(u >> 16);
}

// Exactly matches where(100v>20, v, log1p(exp(100v))/100):
__device__ __forceinline__ float softplus100(float v) {
    return fmaxf(v, 0.f) + 0.01f * __logf(1.f + __expf(-100.f * fabsf(v)));
}

__device__ __forceinline__ bf16x8 cvt8(const float* __restrict__ p) {
    f32x4 a = *(const f32x4*)p;
    f32x4 b = *(const f32x4*)(p + 4);
    bf16x8 r;
    r[0] = f2bf(a[0]); r[1] = f2bf(a[1]); r[2] = f2bf(a[2]); r[3] = f2bf(a[3]);
    r[4] = f2bf(b[0]); r[5] = f2bf(b[1]); r[6] = f2bf(b[2]); r[7] = f2bf(b[3]);
    return r;
}

__device__ __forceinline__ float2 upk(unsigned v) {   // bf16 pair -> f32 pair (exact)
    return make_float2(__uint_as_float(v << 16), __uint_as_float(v & 0xffff0000u));
}

// Single-point trilinear gather on f32 tables (K2 dense levels + gn_fused).
// With literal R the dense/hashed branch folds at compile time.
__device__ __forceinline__ float2 gather_level(const float* __restrict__ tab, int R,
                                               float x0, float x1, float x2) {
    const float Rm1 = (float)(R - 1);
    float px = x0 * Rm1, py = x1 * Rm1, pz = x2 * Rm1;
    float fx = floorf(px), fy = floorf(py), fz = floorf(pz);
    float wx = px - fx, wy = py - fy, wz = pz - fz;
    int ix = (int)fx, iy = (int)fy, iz = (int)fz;
    ix = max(0, min(ix, R - 1)); iy = max(0, min(iy, R - 1)); iz = max(0, min(iz, R - 1));
    int jx = min(ix + 1, R - 1), jy = min(iy + 1, R - 1), jz = min(iz + 1, R - 1);
    float ax = 1.f - wx, ay = 1.f - wy, az = 1.f - wz;
    float wyz0 = ay * az, wyz1 = wy * az, wyz2 = ay * wz, wyz3 = wy * wz;
    float2 lo[4], hi[4];
    const bool adj = (jx == ix + 1);
    if ((long long)R * R * R <= (long long)HMAP) {   // dense
        unsigned sy = (unsigned)R, sz = (unsigned)(R * R);
        unsigned bases[4] = {(unsigned)iy * sy + (unsigned)iz * sz,
                             (unsigned)jy * sy + (unsigned)iz * sz,
                             (unsigned)iy * sy + (unsigned)jz * sz,
                             (unsigned)jy * sy + (unsigned)jz * sz};
        const float2* t2 = (const float2*)tab;
        #pragma unroll
        for (int k = 0; k < 4; ++k) {
            unsigned i0 = bases[k] + (unsigned)ix;
            if (adj && !(i0 & 1u)) {
                f32x4 q = *(const f32x4*)(tab + ((size_t)i0 << 1));
                lo[k] = make_float2(q[0], q[1]);
                hi[k] = make_float2(q[2], q[3]);
            } else {
                lo[k] = t2[i0];
                hi[k] = t2[bases[k] + (unsigned)jx];
            }
        }
    } else {                                          // hashed
        unsigned hy0 = (unsigned)iy * 2654435761u, hy1 = (unsigned)jy * 2654435761u;
        unsigned hz0 = (unsigned)iz * 805459861u,  hz1 = (unsigned)jz * 805459861u;
        unsigned ms[4] = {hy0 ^ hz0, hy1 ^ hz0, hy0 ^ hz1, hy1 ^ hz1};
        if (adj && ((ix & 1) == 0)) {
            #pragma unroll
            for (int k = 0; k < 4; ++k) {
                unsigned h = ((unsigned)ix ^ ms[k]) & HMASK;
                f32x4 q = *(const f32x4*)(tab + ((size_t)(h & ~1u) << 1));
                float2 e0 = make_float2(q[0], q[1]);
                float2 e1 = make_float2(q[2], q[3]);
                bool sw = (h & 1u) != 0;
                lo[k] = sw ? e1 : e0;
                hi[k] = sw ? e0 : e1;
            }
        } else {
            const float2* t2 = (const float2*)tab;
            #pragma unroll
            for (int k = 0; k < 4; ++k) {
                unsigned hl = ((unsigned)ix ^ ms[k]) & HMASK;
                unsigned hh = ((unsigned)jx ^ ms[k]) & HMASK;
                lo[k] = t2[hl];
                hi[k] = t2[hh];
            }
        }
    }
    float2 r = make_float2(0.f, 0.f);
    float wyz[4] = {wyz0, wyz1, wyz2, wyz3};
    #pragma unroll
    for (int k = 0; k < 4; ++k) {
        float wl = ax * wyz[k], wh = wx * wyz[k];
        r.x += wl * lo[k].x + wh * hi[k].x;
        r.y += wl * lo[k].y + wh * hi[k].y;
    }
    return r;
}

// Two-point gather on f32 tables (path-B fallback K1).
__device__ __forceinline__ void gather2(const float* __restrict__ tab, int R,
                                        float x0A, float x1A, float x2A,
                                        float x0B, float x1B, float x2B,
                                        float2& rA, float2& rB) {
    const float Rm1 = (float)(R - 1);
    float wxv[2], axv[2];
    float wyz[2][4];
    float2 lo[2][4], hi[2][4];
    int ixv[2], jxv[2];
    unsigned basev[2][4];
    const bool dense = (long long)R * R * R <= (long long)HMAP;
    #pragma unroll
    for (int t = 0; t < 2; ++t) {
        const float X0 = t ? x0B : x0A, X1 = t ? x1B : x1A, X2 = t ? x2B : x2A;
        float px = X0 * Rm1, py = X1 * Rm1, pz = X2 * Rm1;
        float fx = floorf(px), fy = floorf(py), fz = floorf(pz);
        float wx = px - fx, wy = py - fy, wz = pz - fz;
        int ix = (int)fx, iy = (int)fy, iz = (int)fz;
        ix = max(0, min(ix, R - 1)); iy = max(0, min(iy, R - 1)); iz = max(0, min(iz, R - 1));
        int jx = min(ix + 1, R - 1), jy = min(iy + 1, R - 1), jz = min(iz + 1, R - 1);
        float ax = 1.f - wx, ay = 1.f - wy, az = 1.f - wz;
        wyz[t][0] = ay * az; wyz[t][1] = wy * az; wyz[t][2] = ay * wz; wyz[t][3] = wy * wz;
        wxv[t] = wx; axv[t] = ax; ixv[t] = ix; jxv[t] = jx;
        if (dense) {
            unsigned sy = (unsigned)R, sz = (unsigned)(R * R);
            basev[t][0] = (unsigned)iy * sy + (unsigned)iz * sz;
            basev[t][1] = (unsigned)jy * sy + (unsigned)iz * sz;
            basev[t][2] = (unsigned)iy * sy + (unsigned)jz * sz;
            basev[t][3] = (unsigned)jy * sy + (unsigned)jz * sz;
        } else {
            unsigned hy0 = (unsigned)iy * 2654435761u, hy1 = (unsigned)jy * 2654435761u;
            unsigned hz0 = (unsigned)iz * 805459861u,  hz1 = (unsigned)jz * 805459861u;
            basev[t][0] = hy0 ^ hz0; basev[t][1] = hy1 ^ hz0;
            basev[t][2] = hy0 ^ hz1; basev[t][3] = hy1 ^ hz1;
        }
    }
    if (dense) {
        const float2* t2 = (const float2*)tab;
        #pragma unroll
        for (int t = 0; t < 2; ++t) {
            const bool adj = (jxv[t] == ixv[t] + 1);
            #pragma unroll
            for (int k = 0; k < 4; ++k) {
                unsigned i0 = basev[t][k] + (unsigned)ixv[t];
                if (adj && !(i0 & 1u)) {
                    f32x4 q = *(const f32x4*)(tab + ((size_t)i0 << 1));
                    lo[t][k] = make_float2(q[0], q[1]);
                    hi[t][k] = make_float2(q[2], q[3]);
                } else {
                    lo[t][k] = t2[i0];
                    hi[t][k] = t2[basev[t][k] + (unsigned)jxv[t]];
                }
            }
        }
    } else {
        const float2* t2 = (const float2*)tab;
        #pragma unroll
        for (int t = 0; t < 2; ++t) {
            const bool adj = (jxv[t] == ixv[t] + 1) && ((ixv[t] & 1) == 0);
            #pragma unroll
            for (int k = 0; k < 4; ++k) {
                if (adj) {
                    unsigned h = ((unsigned)ixv[t] ^ basev[t][k]) & HMASK;
                    f32x4 q = *(const f32x4*)(tab + ((size_t)(h & ~1u) << 1));
                    float2 e0 = make_float2(q[0], q[1]);
                    float2 e1 = make_float2(q[2], q[3]);
                    bool sw = (h & 1u) != 0;
                    lo[t][k] = sw ? e1 : e0;
                    hi[t][k] = sw ? e0 : e1;
                } else {
                    unsigned hl = ((unsigned)ixv[t] ^ basev[t][k]) & HMASK;
                    unsigned hh = ((unsigned)jxv[t] ^ basev[t][k]) & HMASK;
                    lo[t][k] = t2[hl];
                    hi[t][k] = t2[hh];
                }
            }
        }
    }
    float2 res[2];
    #pragma unroll
    for (int t = 0; t < 2; ++t) {
        float2 r = make_float2(0.f, 0.f);
        #pragma unroll
        for (int k = 0; k < 4; ++k) {
            float wl = axv[t] * wyz[t][k], wh = wxv[t] * wyz[t][k];
            r.x += wl * lo[t][k].x + wh * hi[t][k].x;
            r.y += wl * lo[t][k].y + wh * hi[t][k].y;
        }
        res[t] = r;
    }
    rA = res[0]; rB = res[1];
}

// Two-point HASHED gather on bf16-pair (u32) tables.
__device__ __forceinline__ void gather2h(const unsigned* __restrict__ tab, int R,
                                         float x0A, float x1A, float x2A,
                                         float x0B, float x1B, float x2B,
                                         float2& rA, float2& rB) {
    const float Rm1 = (float)(R - 1);
    float wxv[2], axv[2], wyz[2][4];
    int ixv[2], jxv[2];
    bool adjv[2];
    unsigned msv[2][4];
    #pragma unroll
    for (int t = 0; t < 2; ++t) {
        const float X0 = t ? x0B : x0A, X1 = t ? x1B : x1A, X2 = t ? x2B : x2A;
        float px = X0 * Rm1, py = X1 * Rm1, pz = X2 * Rm1;
        float fx = floorf(px), fy = floorf(py), fz = floorf(pz);
        float wx = px - fx, wy = py - fy, wz = pz - fz;
        int ix = (int)fx, iy = (int)fy, iz = (int)fz;
        ix = max(0, min(ix, R - 1)); iy = max(0, min(iy, R - 1)); iz = max(0, min(iz, R - 1));
        int jx = min(ix + 1, R - 1), jy = min(iy + 1, R - 1), jz = min(iz + 1, R - 1);
        float ax = 1.f - wx, ay = 1.f - wy, az = 1.f - wz;
        wyz[t][0] = ay * az; wyz[t][1] = wy * az; wyz[t][2] = ay * wz; wyz[t][3] = wy * wz;
        wxv[t] = wx; axv[t] = ax; ixv[t] = ix; jxv[t] = jx;
        adjv[t] = (jx == ix + 1) && ((ix & 1) == 0);
        unsigned hy0 = (unsigned)iy * 2654435761u, hy1 = (unsigned)jy * 2654435761u;
        unsigned hz0 = (unsigned)iz * 805459861u,  hz1 = (unsigned)jz * 805459861u;
        msv[t][0] = hy0 ^ hz0; msv[t][1] = hy1 ^ hz0;
        msv[t][2] = hy0 ^ hz1; msv[t][3] = hy1 ^ hz1;
    }
    float2 lo[2][4], hi[2][4];
    #pragma unroll
    for (int t = 0; t < 2; ++t) {
        #pragma unroll
        for (int k = 0; k < 4; ++k) {
            if (adjv[t]) {
                unsigned h = ((unsigned)ixv[t] ^ msv[t][k]) & HMASK;
                u32x2 q = *(const u32x2*)(tab + (h & ~1u));   // 8B aligned
                float2 e0 = upk(q[0]), e1 = upk(q[1]);
                bool sw = (h & 1u) != 0;
                lo[t][k] = sw ? e1 : e0;
                hi[t][k] = sw ? e0 : e1;
            } else {
                unsigned hl = ((unsigned)ixv[t] ^ msv[t][k]) & HMASK;
                unsigned hh = ((unsigned)jxv[t] ^ msv[t][k]) & HMASK;
                lo[t][k] = upk(tab[hl]);
                hi[t][k] = upk(tab[hh]);
            }
        }
    }
    float2 res[2];
    #pragma unroll
    for (int t = 0; t < 2; ++t) {
        float2 r = make_float2(0.f, 0.f);
        #pragma unroll
        for (int k = 0; k < 4; ++k) {
            float wl = axv[t] * wyz[t][k], wh = wxv[t] * wyz[t][k];
            r.x += wl * lo[t][k].x + wh * hi[t][k].x;
            r.y += wl * lo[t][k].y + wh * hi[t][k].y;
        }
        res[t] = r;
    }
    rA = res[0]; rB = res[1];
}

// =================== Kernel 0: convert hashed tables (5..15) to bf16 pairs ===================
__global__ __launch_bounds__(256)
void cvt_tables(const float* __restrict__ tables, unsigned* __restrict__ tbf) {
    const size_t i = (size_t)blockIdx.x * 256 + threadIdx.x;   // < 11 * HMAP
    const f32x2* src = (const f32x2*)(tables + (size_t)5 * 2 * HMAP);
    f32x2 f = __builtin_nontemporal_load(src + i);
    unsigned v = (unsigned)f2bf(f[0]) | ((unsigned)f2bf(f[1]) << 16);
    __builtin_nontemporal_store(v, tbf + i);
}

// =================== Kernel 1: hashed-level gather, XCD-balanced ===================
// Per-XCD L2 budget = 2 bf16 tables (4MB). Assignment (unit = one level's points):
//   fulls: L5..L12 -> XCD 0..7 (1.0 each)
//   splits: L13 over XCD{0,1,2} (1/3), L14 over XCD{3,4,5} (1/3), L15 over XCD{6,7} (1/2)
// -> max per-XCD load 1.5 units vs previous pairing's 2.0.
// Blocks: grid 8*3072; XCD j = blockIdx%8 (HW round-robin), row i = blockIdx/8.
// Chunk = 512 points (2/thread). 2048 chunks per level (N = 2^20).
__global__ __launch_bounds__(256, 6)
void gather_hashed(const float* __restrict__ x, const unsigned* __restrict__ tbf,
                   unsigned* __restrict__ feat, int N) {
    const int j = blockIdx.x & 7;
    const int i = blockIdx.x >> 3;
    int level, chunk;
    if (i < 2048) {
        level = 5 + j; chunk = i;
    } else {
        const int r = i - 2048;
        if (j < 3) {
            const int share = (j == 2) ? 682 : 683;
            if (r >= share) return;
            level = 13; chunk = j * 683 + r;
        } else if (j < 6) {
            const int jj = j - 3;
            const int share = (jj == 2) ? 682 : 683;
            if (r >= share) return;
            level = 14; chunk = jj * 683 + r;
        } else {
            if (r >= 1024) return;
            level = 15; chunk = (j - 6) * 1024 + r;
        }
    }
    const size_t p0 = (size_t)chunk * 512 + 2u * threadIdx.x;
    const f32x2* xv = (const f32x2*)(x + 3 * p0);     // 12*p0 bytes, p0 even -> 8B aligned
    f32x2 u0 = __builtin_nontemporal_load(xv);
    f32x2 u1 = __builtin_nontemporal_load(xv + 1);
    f32x2 u2 = __builtin_nontemporal_load(xv + 2);
    float2 fA, fB;
    gather2h(tbf + (size_t)(level - 5) * HMAP, c_res[level],
             u0[0], u0[1], u1[0],
             u1[1], u2[0], u2[1],
             fA, fB);
    u32x2 v;
    v[0] = (unsigned)f2bf(fA.x) | ((unsigned)f2bf(fA.y) << 16);
    v[1] = (unsigned)f2bf(fB.x) | ((unsigned)f2bf(fB.y) << 16);
    __builtin_nontemporal_store(v, (u32x2*)(feat + (size_t)(level - 5) * N + p0));
}

// ======================= Kernel 2: tiled embed + dense gathers + MFMA MLP =======================
#define NPB       128                     // points per tile
#define TILES     8
#define PTS_BLK   (NPB * TILES)           // 1024 points per block
#define SA_STRIDE 104                     // shorts; 208B row stride
#define SW0_OFF   (128 * 104)             // W0 bf16 [64][104], cols 71..95 zero
#define SMEM_SHORTS (SW0_OFF + 64 * 104)  // 39936 B -> 4 blocks/CU

__global__ __launch_bounds__(256, 4)
void mlp_tiled2(const float* __restrict__ x, const float* __restrict__ tables,
                const unsigned* __restrict__ feat,
                const float* __restrict__ W0, const float* __restrict__ b0,
                const float* __restrict__ W1, const float* __restrict__ b1,
                const float* __restrict__ W2, const float* __restrict__ b2,
                float* __restrict__ out, int N) {
    __shared__ unsigned short smem[SMEM_SHORTS];
    const int tid  = threadIdx.x;
    const int blk  = blockIdx.x;
    const int wave = tid >> 6, lane = tid & 63;
    const int mhalf = (wave & 1) * 64;
    const int nhalf = (wave >> 1);
    const int lrow = lane & 15, quad = lane >> 4;

    for (int i = tid; i < 64 * 104; i += 256) {
        int n = i / 104, k = i - n * 104;
        smem[SW0_OFF + i] = (k < 71) ? f2bf(W0[n * 71 + k]) : (unsigned short)0;
    }
    for (int i = tid; i < 128 * 25; i += 256) {
        int p = i / 25, k = i - p * 25;
        smem[p * SA_STRIDE + 71 + k] = 0;
    }
    bf16x8 w1f[2][2];
    #pragma unroll
    for (int ks = 0; ks < 2; ++ks)
        #pragma unroll
        for (int nt = 0; nt < 2; ++nt) {
            int n = nhalf * 32 + nt * 16 + lrow;
            w1f[ks][nt] = cvt8(W1 + n * 64 + ks * 32 + quad * 8);
        }
    bf16x8 w2f[2];
    {
        int n2 = nhalf * 16 + lrow;
        #pragma unroll
        for (int ks = 0; ks < 2; ++ks) {
            if (n2 < 17) w2f[ks] = cvt8(W2 + n2 * 64 + ks * 32 + quad * 8);
            else { bf16x8 z = {0,0,0,0,0,0,0,0}; w2f[ks] = z; }
        }
    }
    float b0v[2], b1v[2], b2v;
    #pragma unroll
    for (int nt = 0; nt < 2; ++nt) {
        b0v[nt] = b0[nhalf * 32 + nt * 16 + lrow];
        b1v[nt] = b1[nhalf * 32 + nt * 16 + lrow];
    }
    { int c2 = nhalf * 16 + lrow; b2v = (c2 < 17) ? b2[c2] : 0.f; }
    __syncthreads();

    const size_t pbase0 = (size_t)blk * PTS_BLK;
    #pragma unroll 1
    for (int t = 0; t < TILES; ++t) {
        const size_t pb = pbase0 + (size_t)t * NPB;
        {
            const int p = tid & 127;
            const size_t gp = pb + p;
            unsigned short* row = &smem[p * SA_STRIDE];
            const float x0 = __builtin_nontemporal_load(x + 3 * gp);
            const float x1 = __builtin_nontemporal_load(x + 3 * gp + 1);
            const float x2 = __builtin_nontemporal_load(x + 3 * gp + 2);
            // sin/cos of x*2^m via one sincos + double-angle recurrence:
            // s_{2a}=2 s c, c_{2a}=1-2 s^2  (error ~1e-5 << bf16 rounding)
            float sa, ca, sb, cb, sc, cc;
            __sincosf(x0, &sa, &ca);
            __sincosf(x1, &sb, &cb);
            __sincosf(x2, &sc, &cc);
            if (tid < 128) {
                row[0] = f2bf(x0); row[1] = f2bf(x1); row[2] = f2bf(x2);
                #pragma unroll
                for (int m = 0; m < 6; ++m) {
                    row[3 + 6 * m + 0] = f2bf(sa);
                    row[3 + 6 * m + 1] = f2bf(sb);
                    row[3 + 6 * m + 2] = f2bf(sc);
                    float nsa = 2.f * sa * ca, nca = 1.f - 2.f * sa * sa;
                    float nsb = 2.f * sb * cb, ncb = 1.f - 2.f * sb * sb;
                    float nsc = 2.f * sc * cc, ncc = 1.f - 2.f * sc * sc;
                    sa = nsa; ca = nca; sb = nsb; cb = ncb; sc = nsc; cc = ncc;
                }
                float2 f;
                f = gather_level(tables,                         16, x0, x1, x2);
                row[39] = f2bf(f.x); row[40] = f2bf(f.y);
                f = gather_level(tables + (size_t)1 * 2 * HMAP,  23, x0, x1, x2);
                row[41] = f2bf(f.x); row[42] = f2bf(f.y);
                f = gather_level(tables + (size_t)2 * 2 * HMAP,  31, x0, x1, x2);
                row[43] = f2bf(f.x); row[44] = f2bf(f.y);
            } else {
                #pragma unroll
                for (int m = 0; m < 6; ++m) {
                    row[3 + 6 * m + 3] = f2bf(ca);
                    row[3 + 6 * m + 4] = f2bf(cb);
                    row[3 + 6 * m + 5] = f2bf(cc);
                    float nsa = 2.f * sa * ca, nca = 1.f - 2.f * sa * sa;
                    float nsb = 2.f * sb * cb, ncb = 1.f - 2.f * sb * sb;
                    float nsc = 2.f * sc * cc, ncc = 1.f - 2.f * sc * sc;
                    sa = nsa; ca = nca; sb = nsb; cb = ncb; sc = nsc; cc = ncc;
                }
                float2 f;
                f = gather_level(tables + (size_t)3 * 2 * HMAP,  43, x0, x1, x2);
                row[45] = f2bf(f.x); row[46] = f2bf(f.y);
                f = gather_level(tables + (size_t)4 * 2 * HMAP,  59, x0, x1, x2);
                row[47] = f2bf(f.x); row[48] = f2bf(f.y);
                #pragma unroll
                for (int li = 0; li < 11; ++li) {
                    unsigned v = __builtin_nontemporal_load(feat + (size_t)li * N + gp);
                    row[49 + 2 * li] = (unsigned short)(v & 0xffffu);
                    row[50 + 2 * li] = (unsigned short)(v >> 16);
                }
            }
        }
        __syncthreads();

        f32x4 acc0[4][2];
        #pragma unroll
        for (int mt = 0; mt < 4; ++mt)
            #pragma unroll
            for (int nt = 0; nt < 2; ++nt) acc0[mt][nt] = (f32x4){0.f, 0.f, 0.f, 0.f};
        #pragma unroll
        for (int ks = 0; ks < 3; ++ks) {
            bf16x8 bfr[2];
            #pragma unroll
            for (int nt = 0; nt < 2; ++nt) {
                int n = nhalf * 32 + nt * 16 + lrow;
                bfr[nt] = *(const bf16x8*)&smem[SW0_OFF + n * 104 + ks * 32 + quad * 8];
            }
            #pragma unroll
            for (int mt = 0; mt < 4; ++mt) {
                int m = mhalf + mt * 16 + lrow;
                bf16x8 afr = *(const bf16x8*)&smem[m * SA_STRIDE + ks * 32 + quad * 8];
                #pragma unroll
                for (int nt = 0; nt < 2; ++nt)
                    acc0[mt][nt] = __builtin_amdgcn_mfma_f32_16x16x32_bf16(afr, bfr[nt], acc0[mt][nt], 0, 0, 0);
            }
        }
        __syncthreads();
        #pragma unroll
        for (int mt = 0; mt < 4; ++mt)
            #pragma unroll
            for (int nt = 0; nt < 2; ++nt) {
                int colg = nhalf * 32 + nt * 16 + lrow;
                #pragma unroll
                for (int r = 0; r < 4; ++r) {
                    int rowm = mhalf + mt * 16 + quad * 4 + r;
                    smem[rowm * SA_STRIDE + colg] = f2bf(softplus100(acc0[mt][nt][r] + b0v[nt]));
                }
            }
        __syncthreads();

        f32x4 acc1[4][2];
        #pragma unroll
        for (int mt = 0; mt < 4; ++mt)
            #pragma unroll
            for (int nt = 0; nt < 2; ++nt) acc1[mt][nt] = (f32x4){0.f, 0.f, 0.f, 0.f};
        #pragma unroll
        for (int ks = 0; ks < 2; ++ks) {
            #pragma unroll
            for (int mt = 0; mt < 4; ++mt) {
                int m = mhalf + mt * 16 + lrow;
                bf16x8 afr = *(const bf16x8*)&smem[m * SA_STRIDE + ks * 32 + quad * 8];
                #pragma unroll
                for (int nt = 0; nt < 2; ++nt)
                    acc1[mt][nt] = __builtin_amdgcn_mfma_f32_16x16x32_bf16(afr, w1f[ks][nt], acc1[mt][nt], 0, 0, 0);
            }
        }
        __syncthreads();
        #pragma unroll
        for (int mt = 0; mt < 4; ++mt)
            #pragma unroll
            for (int nt = 0; nt < 2; ++nt) {
                int colg = nhalf * 32 + nt * 16 + lrow;
                #pragma unroll
                for (int r = 0; r < 4; ++r) {
                    int rowm = mhalf + mt * 16 + quad * 4 + r;
                    smem[rowm * SA_STRIDE + colg] = f2bf(softplus100(acc1[mt][nt][r] + b1v[nt]));
                }
            }
        __syncthreads();

        f32x4 acc2[4];
        #pragma unroll
        for (int mt = 0; mt < 4; ++mt) acc2[mt] = (f32x4){0.f, 0.f, 0.f, 0.f};
        #pragma unroll
        for (int ks = 0; ks < 2; ++ks) {
            #pragma unroll
            for (int mt = 0; mt < 4; ++mt) {
                int m = mhalf + mt * 16 + lrow;
                bf16x8 afr = *(const bf16x8*)&smem[m * SA_STRIDE + ks * 32 + quad * 8];
                acc2[mt] = __builtin_amdgcn_mfma_f32_16x16x32_bf16(afr, w2f[ks], acc2[mt], 0, 0, 0);
            }
        }
        {
            int colg = nhalf * 16 + lrow;
            if (colg < 17) {
                #pragma unroll
                for (int mt = 0; mt < 4; ++mt)
                    #pragma unroll
                    for (int r = 0; r < 4; ++r) {
                        int rowm = mhalf + mt * 16 + quad * 4 + r;
                        __builtin_nontemporal_store(acc2[mt][r] + b2v,
                                                    out + (pb + rowm) * 17 + colg);
                    }
            }
        }
        __syncthreads();
    }
}

// ======================= Path B (verified round-3 kernels) =======================
__global__ __launch_bounds__(256, 6)
void gather_levels(const float* __restrict__ x, const float* __restrict__ tables,
                   unsigned* __restrict__ feat, int N, int C) {
    const int b = blockIdx.x;
    const int half = 8 * C;
    int r, level;
    if (b < half) { r = b; level = r & 7; }
    else          { r = b - half; level = 15 - (r & 7); }
    const size_t p0 = (size_t)(r >> 3) * 512 + 2u * threadIdx.x;
    const f32x2* xv = (const f32x2*)(x + 3 * p0);
    f32x2 u0 = __builtin_nontemporal_load(xv);
    f32x2 u1 = __builtin_nontemporal_load(xv + 1);
    f32x2 u2 = __builtin_nontemporal_load(xv + 2);
    float2 fA, fB;
    gather2(tables + (size_t)level * (2u * HMAP), c_res[level],
            u0[0], u0[1], u1[0],
            u1[1], u2[0], u2[1],
            fA, fB);
    u32x2 v;
    v[0] = (unsigned)f2bf(fA.x) | ((unsigned)f2bf(fA.y) << 16);
    v[1] = (unsigned)f2bf(fB.x) | ((unsigned)f2bf(fB.y) << 16);
    __builtin_nontemporal_store(v, (u32x2*)(feat + (size_t)level * N + p0));
}

__global__ __launch_bounds__(256, 4)
void mlp_tiled(const float* __restrict__ x, const unsigned* __restrict__ feat,
               const float* __restrict__ W0, const float* __restrict__ b0,
               const float* __restrict__ W1, const float* __restrict__ b1,
               const float* __restrict__ W2, const float* __restrict__ b2,
               float* __restrict__ out, int N) {
    __shared__ unsigned short smem[SMEM_SHORTS];
    const int tid  = threadIdx.x;
    const int blk  = blockIdx.x;
    const int wave = tid >> 6, lane = tid & 63;
    const int mhalf = (wave & 1) * 64;
    const int nhalf = (wave >> 1);
    const int lrow = lane & 15, quad = lane >> 4;

    for (int i = tid; i < 64 * 104; i += 256) {
        int n = i / 104, k = i - n * 104;
        smem[SW0_OFF + i] = (k < 71) ? f2bf(W0[n * 71 + k]) : (unsigned short)0;
    }
    for (int i = tid; i < 128 * 25; i += 256) {
        int p = i / 25, k = i - p * 25;
        smem[p * SA_STRIDE + 71 + k] = 0;
    }
    bf16x8 w1f[2][2];
    #pragma unroll
    for (int ks = 0; ks < 2; ++ks)
        #pragma unroll
        for (int nt = 0; nt < 2; ++nt) {
            int n = nhalf * 32 + nt * 16 + lrow;
            w1f[ks][nt] = cvt8(W1 + n * 64 + ks * 32 + quad * 8);
        }
    bf16x8 w2f[2];
    {
        int n2 = nhalf * 16 + lrow;
        #pragma unroll
        for (int ks = 0; ks < 2; ++ks) {
            if (n2 < 17) w2f[ks] = cvt8(W2 + n2 * 64 + ks * 32 + quad * 8);
            else { bf16x8 z = {0,0,0,0,0,0,0,0}; w2f[ks] = z; }
        }
    }
    float b0v[2], b1v[2], b2v;
    #pragma unroll
    for (int nt = 0; nt < 2; ++nt) {
        b0v[nt] = b0[nhalf * 32 + nt * 16 + lrow];
        b1v[nt] = b1[nhalf * 32 + nt * 16 + lrow];
    }
    { int c2 = nhalf * 16 + lrow; b2v = (c2 < 17) ? b2[c2] : 0.f; }
    __syncthreads();

    const size_t pbase0 = (size_t)blk * PTS_BLK;
    #pragma unroll 1
    for (int t = 0; t < TILES; ++t) {
        const size_t pb = pbase0 + (size_t)t * NPB;
        {
            const int p = tid & 127;
            const size_t gp = pb + p;
            unsigned short* row = &smem[p * SA_STRIDE];
            const float x0 = __builtin_nontemporal_load(x + 3 * gp);
            const float x1 = __builtin_nontemporal_load(x + 3 * gp + 1);
            const float x2 = __builtin_nontemporal_load(x + 3 * gp + 2);
            if (tid < 128) {
                row[0] = f2bf(x0); row[1] = f2bf(x1); row[2] = f2bf(x2);
                float fr = 1.f;
                #pragma unroll
                for (int m = 0; m < 6; ++m) {
                    row[3 + 6 * m + 0] = f2bf(__sinf(x0 * fr));
                    row[3 + 6 * m + 1] = f2bf(__sinf(x1 * fr));
                    row[3 + 6 * m + 2] = f2bf(__sinf(x2 * fr));
                    fr *= 2.f;
                }
            } else {
                float fr = 1.f;
                #pragma unroll
                for (int m = 0; m < 6; ++m) {
                    row[3 + 6 * m + 3] = f2bf(__cosf(x0 * fr));
                    row[3 + 6 * m + 4] = f2bf(__cosf(x1 * fr));
                    row[3 + 6 * m + 5] = f2bf(__cosf(x2 * fr));
                    fr *= 2.f;
                }
                #pragma unroll
                for (int l = 0; l < 16; ++l) {
                    unsigned v = __builtin_nontemporal_load(feat + (size_t)l * N + gp);
                    row[39 + 2 * l] = (unsigned short)(v & 0xffffu);
                    row[40 + 2 * l] = (unsigned short)(v >> 16);
                }
            }
        }
        __syncthreads();

        f32x4 acc0[4][2];
        #pragma unroll
        for (int mt = 0; mt < 4; ++mt)
            #pragma unroll
            for (int nt = 0; nt < 2; ++nt) acc0[mt][nt] = (f32x4){0.f, 0.f, 0.f, 0.f};
        #pragma unroll
        for (int ks = 0; ks < 3; ++ks) {
            bf16x8 bfr[2];
            #pragma unroll
            for (int nt = 0; nt < 2; ++nt) {
                int n = nhalf * 32 + nt * 16 + lrow;
                bfr[nt] = *(const bf16x8*)&smem[SW0_OFF + n * 104 + ks * 32 + quad * 8];
            }
            #pragma unroll
            for (int mt = 0; mt < 4; ++mt) {
                int m = mhalf + mt * 16 + lrow;
                bf16x8 afr = *(const bf16x8*)&smem[m * SA_STRIDE + ks * 32 + quad * 8];
                #pragma unroll
                for (int nt = 0; nt < 2; ++nt)
                    acc0[mt][nt] = __builtin_amdgcn_mfma_f32_16x16x32_bf16(afr, bfr[nt], acc0[mt][nt], 0, 0, 0);
            }
        }
        __syncthreads();
        #pragma unroll
        for (int mt = 0; mt < 4; ++mt)
            #pragma unroll
            for (int nt = 0; nt < 2; ++nt) {
                int colg = nhalf * 32 + nt * 16 + lrow;
                #pragma unroll
                for (int r = 0; r < 4; ++r) {
                    int rowm = mhalf + mt * 16 + quad * 4 + r;
                    smem[rowm * SA_STRIDE + colg] = f2bf(softplus100(acc0[mt][nt][r] + b0v[nt]));
                }
            }
        __syncthreads();

        f32x4 acc1[4][2];
        #pragma unroll
        for (int mt = 0; mt < 4; ++mt)
            #pragma unroll
            for (int nt = 0; nt < 2; ++nt) acc1[mt][nt] = (f32x4){0.f, 0.f, 0.f, 0.f};
        #pragma unroll
        for (int ks = 0; ks < 2; ++ks) {
            #pragma unroll
            for (int mt = 0; mt < 4; ++mt) {
                int m = mhalf + mt * 16 + lrow;
                bf16x8 afr = *(const bf16x8*)&smem[m * SA_STRIDE + ks * 32 + quad * 8];
                #pragma unroll
                for (int nt = 0; nt < 2; ++nt)
                    acc1[mt][nt] = __builtin_amdgcn_mfma_f32_16x16x32_bf16(afr, w1f[ks][nt], acc1[mt][nt], 0, 0, 0);
            }
        }
        __syncthreads();
        #pragma unroll
        for (int mt = 0; mt < 4; ++mt)
            #pragma unroll
            for (int nt = 0; nt < 2; ++nt) {
                int colg = nhalf * 32 + nt * 16 + lrow;
                #pragma unroll
                for (int r = 0; r < 4; ++r) {
                    int rowm = mhalf + mt * 16 + quad * 4 + r;
                    smem[rowm * SA_STRIDE + colg] = f2bf(softplus100(acc1[mt][nt][r] + b1v[nt]));
                }
            }
        __syncthreads();

        f32x4 acc2[4];
        #pragma unroll
        for (int mt = 0; mt < 4; ++mt) acc2[mt] = (f32x4){0.f, 0.f, 0.f, 0.f};
        #pragma unroll
        for (int ks = 0; ks < 2; ++ks) {
            #pragma unroll
            for (int mt = 0; mt < 4; ++mt) {
                int m = mhalf + mt * 16 + lrow;
                bf16x8 afr = *(const bf16x8*)&smem[m * SA_STRIDE + ks * 32 + quad * 8];
                acc2[mt] = __builtin_amdgcn_mfma_f32_16x16x32_bf16(afr, w2f[ks], acc2[mt], 0, 0, 0);
            }
        }
        {
            int colg = nhalf * 16 + lrow;
            if (colg < 17) {
                #pragma unroll
                for (int mt = 0; mt < 4; ++mt)
                    #pragma unroll
                    for (int r = 0; r < 4; ++r) {
                        int rowm = mhalf + mt * 16 + quad * 4 + r;
                        __builtin_nontemporal_store(acc2[mt][r] + b2v,
                                                    out + (pb + rowm) * 17 + colg);
                    }
            }
        }
        __syncthreads();
    }
}

// ======================= Fallback (ws too small): fully fused =======================
__global__ __launch_bounds__(256, 3)
void gn_fused(const float* __restrict__ x, const float* __restrict__ tables,
              const float* __restrict__ W0, const float* __restrict__ b0,
              const float* __restrict__ W1, const float* __restrict__ b1,
              const float* __restrict__ W2, const float* __restrict__ b2,
              float* __restrict__ out) {
    __shared__ unsigned short smem[SMEM_SHORTS];
    const int tid = threadIdx.x;
    const int blk = blockIdx.x;
    const int wave = tid >> 6, lane = tid & 63;
    const int mhalf = (wave & 1) * 64;
    const int nhalf = (wave >> 1);
    const int lrow = lane & 15, quad = lane >> 4;
    for (int i = tid; i < 64 * 104; i += 256) {
        int n = i / 104, k = i - n * 104;
        smem[SW0_OFF + i] = (k < 71) ? f2bf(W0[n * 71 + k]) : (unsigned short)0;
    }
    for (int i = tid; i < 128 * 25; i += 256) {
        int p = i / 25, k = i - p * 25;
        smem[p * SA_STRIDE + 71 + k] = 0;
    }
    bf16x8 w1f[2][2];
    #pragma unroll
    for (int ks = 0; ks < 2; ++ks)
        #pragma unroll
        for (int nt = 0; nt < 2; ++nt) {
            int n = nhalf * 32 + nt * 16 + lrow;
            w1f[ks][nt] = cvt8(W1 + n * 64 + ks * 32 + quad * 8);
        }
    bf16x8 w2f[2];
    {
        int n2 = nhalf * 16 + lrow;
        #pragma unroll
        for (int ks = 0; ks < 2; ++ks) {
            if (n2 < 17) w2f[ks] = cvt8(W2 + n2 * 64 + ks * 32 + quad * 8);
            else { bf16x8 z = {0,0,0,0,0,0,0,0}; w2f[ks] = z; }
        }
    }
    float b0v[2], b1v[2], b2v;
    #pragma unroll
    for (int nt = 0; nt < 2; ++nt) {
        b0v[nt] = b0[nhalf * 32 + nt * 16 + lrow];
        b1v[nt] = b1[nhalf * 32 + nt * 16 + lrow];
    }
    { int c2 = nhalf * 16 + lrow; b2v = (c2 < 17) ? b2[c2] : 0.f; }
    {
        const int p = tid & 127;
        const size_t gp = (size_t)blk * NPB + p;
        const float x0 = x[3 * gp], x1 = x[3 * gp + 1], x2 = x[3 * gp + 2];
        unsigned short* row = &smem[p * SA_STRIDE];
        if (tid < 128) {
            row[0] = f2bf(x0); row[1] = f2bf(x1); row[2] = f2bf(x2);
            float fr = 1.f;
            #pragma unroll
            for (int m = 0; m < 6; ++m) {
                row[3 + 6 * m + 0] = f2bf(__sinf(x0 * fr));
                row[3 + 6 * m + 1] = f2bf(__sinf(x1 * fr));
                row[3 + 6 * m + 2] = f2bf(__sinf(x2 * fr));
                fr *= 2.f;
            }
            #pragma unroll
            for (int li = 0; li < 8; ++li) {
                const int l = 2 * li;
                float2 f = gather_level(tables + (size_t)l * (2u * HMAP), c_res[l], x0, x1, x2);
                row[39 + 2 * l] = f2bf(f.x);
                row[40 + 2 * l] = f2bf(f.y);
            }
        } else {
            float fr = 1.f;
            #pragma unroll
            for (int m = 0; m < 6; ++m) {
                row[3 + 6 * m + 3] = f2bf(__cosf(x0 * fr));
                row[3 + 6 * m + 4] = f2bf(__cosf(x1 * fr));
                row[3 + 6 * m + 5] = f2bf(__cosf(x2 * fr));
                fr *= 2.f;
            }
            #pragma unroll
            for (int li = 0; li < 8; ++li) {
                const int l = 2 * li + 1;
                float2 f = gather_level(tables + (size_t)l * (2u * HMAP), c_res[l], x0, x1, x2);
                row[39 + 2 * l] = f2bf(f.x);
                row[40 + 2 * l] = f2bf(f.y);
            }
        }
    }
    __syncthreads();
    f32x4 acc0[4][2];
    #pragma unroll
    for (int mt = 0; mt < 4; ++mt)
        #pragma unroll
        for (int nt = 0; nt < 2; ++nt) acc0[mt][nt] = (f32x4){0.f, 0.f, 0.f, 0.f};
    #pragma unroll
    for (int ks = 0; ks < 3; ++ks) {
        bf16x8 bfr[2];
        #pragma unroll
        for (int nt = 0; nt < 2; ++nt) {
            int n = nhalf * 32 + nt * 16 + lrow;
            bfr[nt] = *(const bf16x8*)&smem[SW0_OFF + n * 104 + ks * 32 + quad * 8];
        }
        #pragma unroll
        for (int mt = 0; mt < 4; ++mt) {
            int m = mhalf + mt * 16 + lrow;
            bf16x8 afr = *(const bf16x8*)&smem[m * SA_STRIDE + ks * 32 + quad * 8];
            #pragma unroll
            for (int nt = 0; nt < 2; ++nt)
                acc0[mt][nt] = __builtin_amdgcn_mfma_f32_16x16x32_bf16(afr, bfr[nt], acc0[mt][nt], 0, 0, 0);
        }
    }
    __syncthreads();
    #pragma unroll
    for (int mt = 0; mt < 4; ++mt)
        #pragma unroll
        for (int nt = 0; nt < 2; ++nt) {
            int colg = nhalf * 32 + nt * 16 + lrow;
            #pragma unroll
            for (int r = 0; r < 4; ++r) {
                int rowm = mhalf + mt * 16 + quad * 4 + r;
                smem[rowm * SA_STRIDE + colg] = f2bf(softplus100(acc0[mt][nt][r] + b0v[nt]));
            }
        }
    __syncthreads();
    f32x4 acc1[4][2];
    #pragma unroll
    for (int mt = 0; mt < 4; ++mt)
        #pragma unroll
        for (int nt = 0; nt < 2; ++nt) acc1[mt][nt] = (f32x4){0.f, 0.f, 0.f, 0.f};
    #pragma unroll
    for (int ks = 0; ks < 2; ++ks) {
        #pragma unroll
        for (int mt = 0; mt < 4; ++mt) {
            int m = mhalf + mt * 16 + lrow;
            bf16x8 afr = *(const bf16x8*)&smem[m * SA_STRIDE + ks * 32 + quad * 8];
            #pragma unroll
            for (int nt = 0; nt < 2; ++nt)
                acc1[mt][nt] = __builtin_amdgcn_mfma_f32_16x16x32_bf16(afr, w1f[ks][nt], acc1[mt][nt], 0, 0, 0);
        }
    }
    __syncthreads();
    #pragma unroll
    for (int mt = 0; mt < 4; ++mt)
        #pragma unroll
        for (int nt = 0; nt < 2; ++nt) {
            int colg = nhalf * 32 + nt * 16 + lrow;
            #pragma unroll
            for (int r = 0; r < 4; ++r) {
                int rowm = mhalf + mt * 16 + quad * 4 + r;
                smem[rowm * SA_STRIDE + colg] = f2bf(softplus100(acc1[mt][nt][r] + b1v[nt]));
            }
        }
    __syncthreads();
    f32x4 acc2[4];
    #pragma unroll
    for (int mt = 0; mt < 4; ++mt) acc2[mt] = (f32x4){0.f, 0.f, 0.f, 0.f};
    #pragma unroll
    for (int ks = 0; ks < 2; ++ks) {
        #pragma unroll
        for (int mt = 0; mt < 4; ++mt) {
            int m = mhalf + mt * 16 + lrow;
            bf16x8 afr = *(const bf16x8*)&smem[m * SA_STRIDE + ks * 32 + quad * 8];
            acc2[mt] = __builtin_amdgcn_mfma_f32_16x16x32_bf16(afr, w2f[ks], acc2[mt], 0, 0, 0);
        }
    }
    {
        int colg = nhalf * 16 + lrow;
        if (colg < 17) {
            #pragma unroll
            for (int mt = 0; mt < 4; ++mt)
                #pragma unroll
                for (int r = 0; r < 4; ++r) {
                    int rowm = mhalf + mt * 16 + quad * 4 + r;
                    out[((size_t)blk * NPB + rowm) * 17 + colg] = acc2[mt][r] + b2v;
                }
        }
    }
}

extern "C" void kernel_launch(void* const* d_in, const int* in_sizes, int n_in,
                              void* d_out, int out_size, void* d_ws, size_t ws_size,
                              hipStream_t stream) {
    const float* x      = (const float*)d_in[0];
    const float* tables = (const float*)d_in[1];
    const float* W0     = (const float*)d_in[2];
    const float* b0     = (const float*)d_in[3];
    const float* W1     = (const float*)d_in[4];
    const float* b1     = (const float*)d_in[5];
    const float* W2     = (const float*)d_in[6];
    const float* b2     = (const float*)d_in[7];
    float* out = (float*)d_out;
    const int n = in_sizes[0] / 3;                           // 1048576
    const size_t featA_b = (size_t)11 * n * 4;               // 44 MB hashed feat staging
    const size_t tbf_b   = (size_t)11 * HMAP * 4;            // 22 MB bf16 tables
    const size_t wsB     = (size_t)16 * n * 4;               // 64 MB (path B)
    if (n == (1 << 20) && ws_size >= featA_b + tbf_b) {
        unsigned* feat = (unsigned*)d_ws;
        unsigned* tbf  = (unsigned*)((char*)d_ws + featA_b);
        cvt_tables<<<dim3(11 * HMAP / 256), dim3(256), 0, stream>>>(tables, tbf);
        gather_hashed<<<dim3(8 * 3072), dim3(256), 0, stream>>>(x, tbf, feat, n);
        mlp_tiled2<<<dim3(n / PTS_BLK), dim3(256), 0, stream>>>(x, tables, feat, W0, b0, W1, b1, W2, b2, out, n);
    } else if (ws_size >= wsB) {
        unsigned* feat = (unsigned*)d_ws;
        const int C = n / 512;
        gather_levels<<<dim3(16 * C), dim3(256), 0, stream>>>(x, tables, feat, n, C);
        mlp_tiled<<<dim3(n / PTS_BLK), dim3(256), 0, stream>>>(x, feat, W0, b0, W1, b1, W2, b2, out, n);
    } else {
        gn_fused<<<dim3(n / NPB), dim3(256), 0, stream>>>(x, tables, W0, b0, W1, b1, W2, b2, out);
    }
}